// Round 9
// baseline (356.376 us; speedup 1.0000x reference)
//
#include <hip/hip_runtime.h>
#include <hip/hip_bf16.h>
#include <stdint.h>

#define B_    256
#define T_    512
#define N_    256
#define START_ 254
#define STOP_  255
#define GCOLS 4           // real batch columns per denominator block
#define NF    64          // forward denominator blocks
#define ND    128         // total denominator blocks (64 fwd + 64 bwd)
#define LOG2E 1.4426950408889634f
#define LN2   0.6931471805599453f

// d_ws: floats [0,65536) alphaF, [65536,131072) betaB, [131072,131328) CF,
// [131328,131584) CB; bytes [1MB, 1MB+67.1MB) bf16 xp = exp(inputs)
#define WSB_OFF 65536
#define WCF_OFF 131072
#define WCB_OFF 131328
#define XP_BYTE_OFF ((size_t)1 << 20)
#define WS_NEED (XP_BYTE_OFF + (size_t)B_ * T_ * N_ * 2)

typedef __attribute__((ext_vector_type(4))) float floatx4;
typedef __attribute__((ext_vector_type(4))) unsigned int uintx4;
typedef __attribute__((ext_vector_type(8))) int v8i;
typedef __attribute__((ext_vector_type(4))) unsigned short ushort4_t;

template<bool X> struct BC { static constexpr bool value = X; };

__device__ __forceinline__ void lds_barrier() {
    asm volatile("s_waitcnt lgkmcnt(0)\n\ts_barrier" ::: "memory");
}

__device__ __forceinline__ unsigned short f2bf(float f) {   // RNE
    uint32_t u = __builtin_bit_cast(uint32_t, f);
    u = (u + 0x7FFFu + ((u >> 16) & 1u)) >> 16;
    return (unsigned short)u;
}
__device__ __forceinline__ float bf2f(unsigned short h) {
    return __builtin_bit_cast(float, (uint32_t)h << 16);
}
__device__ __forceinline__ int pk_fp8x4(float a, float b, float c, float d) {  // e4m3
    int r = __builtin_amdgcn_cvt_pk_fp8_f32(a, b, 0, false);
    return __builtin_amdgcn_cvt_pk_fp8_f32(c, d, r, true);
}
__device__ __forceinline__ int pk_bf8x4(float a, float b, float c, float d) {  // e5m2
    int r = __builtin_amdgcn_cvt_pk_bf8_f32(a, b, 0, false);
    return __builtin_amdgcn_cvt_pk_bf8_f32(c, d, r, true);
}

// V layout (per buffer, 4096 B): element (k, col b):
//   addr = (((k>>7)*2 + ((k>>4)&1))<<10) + (((k>>5)&3)<<8) + (b<<4) + (k&15)
// Lane l reads two b128 per page pair -> contiguous 1KB/wave, zero conflicts;
// lane's 32 B = k in [c*128+q*32, +32) == f8f6f4 operand byte order (verified r8).
struct DenomShared {
    alignas(16) char  V[2][4096];
    alignas(16) float mbuf[16 * 36];   // per-lane max partials [b][w*4+q]
    alignas(16) float sbuf[16 * 20];   // sum partials (mask-dead path only)
    int flag;
};

// 512 threads = 8 waves; wave w owns rows [32w,32w+32) as 2 M-tiles.
// Lane l: q=l>>4, b=l&15 (MFMA column; real iff b<GCOLS — others stay 0).
// A = E (e4m3, fwd) / E^T (bwd) persistent in VGPRs. B = V (e5m2) in LDS.
// PRE: emit stream is precomputed bf16 exp(inputs) from d_ws (2 KB/step/CU).
template<bool ISF, bool PRE>
__device__ __forceinline__ void denom_path(
    DenomShared& sh, const float* __restrict__ inputs,
    const float* __restrict__ trans, const int* __restrict__ mask,
    const unsigned short* __restrict__ xp,
    float* __restrict__ ws, int blkLocal)
{
    const int tid = threadIdx.x;
    const int w = tid >> 6;
    const int l = tid & 63;
    const int q = l >> 4;
    const int b = l & 15;
    const bool real = (b < GCOLS);
    const int bgc = blkLocal * GCOLS + (real ? b : 0);   // clamped row index
    const int j0 = 32 * w + 4 * q;          // + 16*mt
    const int S = ISF ? 256 : 255;          // serial steps after init
    const int scl = 0x7F7F7F7F;             // e8m0 scale = 1.0

    auto EIDX = [](int s) { return ISF ? s : (511 - s); };
    auto MIDX = [](int s) { return ISF ? (s - 1) : (511 - s); };

    // V write addresses (one b32 per mt): state j = 32w+16mt+4q+rr
    int wa[2];
    #pragma unroll
    for (int mt = 0; mt < 2; ++mt)
        wa[mt] = ((((2 * w + mt) >> 3) * 2 + mt) << 10)
               + ((w & 3) << 8) + (b << 4) + (q << 2);
    const int rbase = l << 4;

    // ---- persistent A-fragments (e4m3): lane holds E[row][c*128+q*32 .. +32)
    v8i afrag[2][2];
    #pragma unroll
    for (int mt = 0; mt < 2; ++mt) {
        const int row = 32 * w + 16 * mt + b;
        #pragma unroll
        for (int c = 0; c < 2; ++c) {
            v8i a;
            #pragma unroll
            for (int g8 = 0; g8 < 8; ++g8) {
                float e[4];
                if (ISF) {
                    floatx4 t = *(const floatx4*)(trans + row * N_ + c * 128 + q * 32 + 4 * g8);
                    #pragma unroll
                    for (int ii = 0; ii < 4; ++ii)
                        e[ii] = __builtin_amdgcn_exp2f(t[ii] * LOG2E);
                } else {
                    #pragma unroll
                    for (int ii = 0; ii < 4; ++ii) {
                        const int k = c * 128 + q * 32 + 4 * g8 + ii;
                        e[ii] = __builtin_amdgcn_exp2f(trans[k * N_ + row] * LOG2E);
                    }
                }
                a[g8] = pk_fp8x4(e[0], e[1], e[2], e[3]);
            }
            afrag[mt][c] = a;
        }
    }

    // ---- mask-dead scan (once): any zero mask in this block's GCOLS columns?
    {
        const int* mrow = mask + blkLocal * GCOLS * T_;
        bool hd = false;
        #pragma unroll
        for (int i = 0; i < GCOLS * T_ / 512; ++i)
            hd |= (mrow[tid + 512 * i] == 0);
        if (tid == 0) sh.flag = 0;
        __syncthreads();
        if (__any(hd) && l == 0) atomicOr(&sh.flag, 1);
        __syncthreads();
    }
    const bool anyDead = (sh.flag != 0);

    const float* emitp = inputs + (size_t)bgc * T_ * N_;
    const unsigned short* xprow = xp + (size_t)bgc * T_ * N_;
    const int* maskp = mask + bgc * T_;
    float C = 0.f;
    float u[2][4];

    // ---- init (s=0)
    if (ISF) {   // u = exp(trans[:,START]) * exp(emit0); 0 for unused cols
        float x0[2][4] = {};
        if constexpr (PRE) {
            if (real) {
                ushort4_t h0 = *(const ushort4_t*)(xprow + j0);
                ushort4_t h1 = *(const ushort4_t*)(xprow + j0 + 16);
                #pragma unroll
                for (int r = 0; r < 4; ++r) { x0[0][r] = bf2f(h0[r]); x0[1][r] = bf2f(h1[r]); }
            }
        } else {
            if (real) {
                floatx4 e0 = *(const floatx4*)(emitp + j0);
                floatx4 e1 = *(const floatx4*)(emitp + j0 + 16);
                #pragma unroll
                for (int r = 0; r < 4; ++r) {
                    x0[0][r] = __builtin_amdgcn_exp2f(e0[r] * LOG2E);
                    x0[1][r] = __builtin_amdgcn_exp2f(e1[r] * LOG2E);
                }
            }
        }
        #pragma unroll
        for (int mt = 0; mt < 2; ++mt)
            #pragma unroll
            for (int r = 0; r < 4; ++r) {
                const int j = j0 + 16 * mt + r;
                u[mt][r] = __builtin_amdgcn_exp2f(trans[j * N_ + START_] * LOG2E) * x0[mt][r];
            }
    } else {     // u = exp(trans[STOP,:]); V_0 = u * exp(emit 511) (0 unused)
        #pragma unroll
        for (int mt = 0; mt < 2; ++mt) {
            floatx4 st = *(const floatx4*)(trans + STOP_ * N_ + j0 + 16 * mt);
            #pragma unroll
            for (int r = 0; r < 4; ++r)
                u[mt][r] = __builtin_amdgcn_exp2f(st[r] * LOG2E);
        }
    }
    {   // init produce + V0 write
        float mx = u[0][0], sm = 0.f;
        #pragma unroll
        for (int mt = 0; mt < 2; ++mt)
            #pragma unroll
            for (int r = 0; r < 4; ++r) { mx = fmaxf(mx, u[mt][r]); sm += u[mt][r]; }
        sh.mbuf[b * 36 + w * 4 + q] = mx;
        sm += __shfl_xor(sm, 32, 64);
        if (l < 32) sh.sbuf[b * 20 + w * 2 + q] = sm;

        float xpi[2][4] = {};
        if (ISF) {
            #pragma unroll
            for (int mt = 0; mt < 2; ++mt)
                #pragma unroll
                for (int r = 0; r < 4; ++r) xpi[mt][r] = 1.f;
        } else {
            if constexpr (PRE) {
                if (real) {
                    ushort4_t h0 = *(const ushort4_t*)(xprow + (size_t)511 * N_ + j0);
                    ushort4_t h1 = *(const ushort4_t*)(xprow + (size_t)511 * N_ + j0 + 16);
                    #pragma unroll
                    for (int r = 0; r < 4; ++r) { xpi[0][r] = bf2f(h0[r]); xpi[1][r] = bf2f(h1[r]); }
                }
            } else {
                if (real) {
                    floatx4 e0 = *(const floatx4*)(emitp + (size_t)511 * N_ + j0);
                    floatx4 e1 = *(const floatx4*)(emitp + (size_t)511 * N_ + j0 + 16);
                    #pragma unroll
                    for (int r = 0; r < 4; ++r) {
                        xpi[0][r] = __builtin_amdgcn_exp2f(e0[r] * LOG2E);
                        xpi[1][r] = __builtin_amdgcn_exp2f(e1[r] * LOG2E);
                    }
                }
            }
        }
        #pragma unroll
        for (int mt = 0; mt < 2; ++mt)
            *(int*)(sh.V[0] + wa[mt]) =
                pk_bf8x4(u[mt][0] * xpi[mt][0], u[mt][1] * xpi[mt][1],
                         u[mt][2] * xpi[mt][2], u[mt][3] * xpi[mt][3]);
    }

    auto run = [&](auto fastc) {
        constexpr bool FAST = decltype(fastc)::value;
        ushort4_t ebh[2][2] = {};
        floatx4   ebf[2][2] = {};
        float     mrot[2] = {1.f, 1.f};
        #pragma unroll
        for (int i = 0; i < 2; ++i) {
            if constexpr (PRE) {
                if (real) {
                    ebh[i][0] = *(const ushort4_t*)(xprow + (size_t)EIDX(i + 1) * N_ + j0);
                    ebh[i][1] = *(const ushort4_t*)(xprow + (size_t)EIDX(i + 1) * N_ + j0 + 16);
                }
            } else {
                if (real) {
                    ebf[i][0] = *(const floatx4*)(emitp + (size_t)EIDX(i + 1) * N_ + j0);
                    ebf[i][1] = *(const floatx4*)(emitp + (size_t)EIDX(i + 1) * N_ + j0 + 16);
                }
            }
            if (!FAST) mrot[i] = (float)maskp[MIDX(i + 1)];
        }
        lds_barrier();

        auto body = [&](int s, int pr, int cur) {
            const int sp = (s + 2 <= S) ? s + 2 : S;   // distance-2 prefetch
            ushort4_t hC0 = {}, hC1 = {};
            floatx4   fC0 = {}, fC1 = {};
            if constexpr (PRE) {
                if (real) {
                    hC0 = *(const ushort4_t*)(xprow + (size_t)EIDX(sp) * N_ + j0);
                    hC1 = *(const ushort4_t*)(xprow + (size_t)EIDX(sp) * N_ + j0 + 16);
                }
            } else {
                if (real) {
                    fC0 = *(const floatx4*)(emitp + (size_t)EIDX(sp) * N_ + j0);
                    fC1 = *(const floatx4*)(emitp + (size_t)EIDX(sp) * N_ + j0 + 16);
                }
            }
            float mC = 1.f;
            if (!FAST) mC = (float)maskp[MIDX(sp)];

            // B fragments: 4 contiguous b128 (zero conflicts)
            const char* vb = sh.V[pr];
            v8i bfrag[2];
            #pragma unroll
            for (int c = 0; c < 2; ++c) {
                uintx4 r0 = *(const uintx4*)(vb + (c << 11) + rbase);
                uintx4 r1 = *(const uintx4*)(vb + (c << 11) + 1024 + rbase);
                v8i bf;
                bf[0] = r0[0]; bf[1] = r0[1]; bf[2] = r0[2]; bf[3] = r0[3];
                bf[4] = r1[0]; bf[5] = r1[1]; bf[6] = r1[2]; bf[7] = r1[3];
                bfrag[c] = bf;
            }

            // consume lag-1 stats (hidden under MFMA wait) -> max -> pow2
            const float* mb = &sh.mbuf[b * 36];
            float cmax;
            {
                floatx4 mm[8];
                #pragma unroll
                for (int i = 0; i < 8; ++i) mm[i] = *(const floatx4*)(mb + 4 * i);
                floatx4 mv = mm[0];
                #pragma unroll
                for (int i = 1; i < 8; ++i)
                    #pragma unroll
                    for (int r = 0; r < 4; ++r) mv[r] = fmaxf(mv[r], mm[i][r]);
                cmax = fmaxf(fmaxf(mv[0], mv[1]), fmaxf(mv[2], mv[3]));
            }
            const uint32_t cb = __builtin_bit_cast(uint32_t, cmax);
            const int eb = (int)((cb >> 23) & 0xFFu);
            const float rs = __builtin_bit_cast(float, (uint32_t)(249 - eb) << 23); // 2^(122-eb)
            const float dCf = (float)(122 - eb);

            // xp for this step
            float xpv[2][4];
            if constexpr (PRE) {
                #pragma unroll
                for (int r = 0; r < 4; ++r) {
                    xpv[0][r] = bf2f(ebh[cur][0][r]);
                    xpv[1][r] = bf2f(ebh[cur][1][r]);
                }
            } else {
                #pragma unroll
                for (int r = 0; r < 4; ++r) {
                    if (ISF) {
                        xpv[0][r] = __builtin_amdgcn_exp2f(fmaf(ebf[cur][0][r], LOG2E, dCf));
                        xpv[1][r] = __builtin_amdgcn_exp2f(fmaf(ebf[cur][1][r], LOG2E, dCf));
                    } else {
                        xpv[0][r] = __builtin_amdgcn_exp2f(ebf[cur][0][r] * LOG2E);
                        xpv[1][r] = __builtin_amdgcn_exp2f(ebf[cur][1][r] * LOG2E);
                    }
                }
            }

            floatx4 a0 = {0.f,0.f,0.f,0.f}, a1 = {0.f,0.f,0.f,0.f};
            a0 = __builtin_amdgcn_mfma_scale_f32_16x16x128_f8f6f4(
                     afrag[0][0], bfrag[0], a0, 0, 1, 0, scl, 0, scl);
            a1 = __builtin_amdgcn_mfma_scale_f32_16x16x128_f8f6f4(
                     afrag[1][0], bfrag[0], a1, 0, 1, 0, scl, 0, scl);
            a0 = __builtin_amdgcn_mfma_scale_f32_16x16x128_f8f6f4(
                     afrag[0][1], bfrag[1], a0, 0, 1, 0, scl, 0, scl);
            a1 = __builtin_amdgcn_mfma_scale_f32_16x16x128_f8f6f4(
                     afrag[1][1], bfrag[1], a1, 0, 1, 0, scl, 0, scl);

            if (FAST) {
                #pragma unroll
                for (int r = 0; r < 4; ++r) {
                    if (ISF) {
                        if (PRE) { u[0][r] = (a0[r] * rs) * xpv[0][r];
                                   u[1][r] = (a1[r] * rs) * xpv[1][r]; }
                        else     { u[0][r] = a0[r] * xpv[0][r];   // dCf folded
                                   u[1][r] = a1[r] * xpv[1][r]; }
                    } else {
                        u[0][r] = a0[r] * rs;
                        u[1][r] = a1[r] * rs;
                    }
                }
            } else {
                const bool live = (mrot[cur] != 0.f);
                float csv = 0.f;
                if (__any(!live)) {
                    const float* sb = &sh.sbuf[b * 20];
                    floatx4 s0 = *(const floatx4*)sb,       s1 = *(const floatx4*)(sb + 4);
                    floatx4 s2 = *(const floatx4*)(sb + 8), s3 = *(const floatx4*)(sb + 12);
                    csv = ((((s0[0] + s0[1]) + (s0[2] + s0[3])) +
                            ((s1[0] + s1[1]) + (s1[2] + s1[3]))) +
                           (((s2[0] + s2[1]) + (s2[2] + s2[3])) +
                            ((s3[0] + s3[1]) + (s3[2] + s3[3])))) * rs;
                }
                #pragma unroll
                for (int r = 0; r < 4; ++r) {
                    if (ISF) {
                        if (PRE) { u[0][r] = live ? (a0[r] * rs) * xpv[0][r] : csv;
                                   u[1][r] = live ? (a1[r] * rs) * xpv[1][r] : csv; }
                        else     { u[0][r] = live ? a0[r] * xpv[0][r] : csv;
                                   u[1][r] = live ? a1[r] * xpv[1][r] : csv; }
                    } else {
                        u[0][r] = live ? a0[r] * rs : csv;
                        u[1][r] = live ? a1[r] * rs : csv;
                    }
                }
            }
            C += (float)(eb - 122);

            // produce: zero cross-lane ops before the barrier
            {
                float mx = fmaxf(fmaxf(fmaxf(u[0][0], u[0][1]), fmaxf(u[0][2], u[0][3])),
                                 fmaxf(fmaxf(u[1][0], u[1][1]), fmaxf(u[1][2], u[1][3])));
                sh.mbuf[b * 36 + w * 4 + q] = mx;
                if (!FAST) {
                    float sm = ((u[0][0] + u[0][1]) + (u[0][2] + u[0][3]))
                             + ((u[1][0] + u[1][1]) + (u[1][2] + u[1][3]));
                    sm += __shfl_xor(sm, 32, 64);
                    if (l < 32) sh.sbuf[b * 20 + w * 2 + q] = sm;
                }
            }
            // write V: fwd V=u ; bwd V=u*xp  (unused cols write exact 0)
            #pragma unroll
            for (int mt = 0; mt < 2; ++mt) {
                *(int*)(sh.V[pr ^ 1] + wa[mt]) = ISF
                    ? pk_bf8x4(u[mt][0], u[mt][1], u[mt][2], u[mt][3])
                    : pk_bf8x4(u[mt][0] * xpv[mt][0], u[mt][1] * xpv[mt][1],
                               u[mt][2] * xpv[mt][2], u[mt][3] * xpv[mt][3]);
            }
            lds_barrier();
            if constexpr (PRE) { ebh[cur][0] = hC0; ebh[cur][1] = hC1; }
            else               { ebf[cur][0] = fC0; ebf[cur][1] = fC1; }
            if (!FAST) mrot[cur] = mC;
        };

        #pragma unroll 1
        for (int g = 0; g < 127; ++g) {
            body(2 * g + 1, 0, 0);
            body(2 * g + 2, 1, 1);
        }
        if (ISF) { body(255, 0, 0); body(256, 1, 1); }
        else     { body(255, 0, 0); }
    };

    if (anyDead) run(BC<false>{});
    else         run(BC<true>{});

    // ---- store partials (real columns only)
    if (real) {
        const int bg = blkLocal * GCOLS + b;
        float* wsV = ws + (ISF ? 0 : WSB_OFF);
        #pragma unroll
        for (int mt = 0; mt < 2; ++mt) {
            floatx4 vv = {u[mt][0], u[mt][1], u[mt][2], u[mt][3]};
            *(floatx4*)&wsV[(size_t)bg * N_ + j0 + 16 * mt] = vv;
        }
    }
    if (tid < GCOLS) {
        float* wsC = ws + (ISF ? WCF_OFF : WCB_OFF);
        wsC[blkLocal * GCOLS + tid] = C;
    }
}

// Pre-pass: xp = bf16(exp(inputs)) into d_ws (all 256 CUs, ~40 us)
__global__ __launch_bounds__(512) void crf_prepass(
    const float* __restrict__ in, unsigned short* __restrict__ xp)
{
    const size_t total4 = (size_t)B_ * T_ * N_ / 4;
    size_t i = (size_t)blockIdx.x * 512 + threadIdx.x;
    const size_t stride = (size_t)gridDim.x * 512;
    for (; i < total4; i += stride) {
        floatx4 v = *(const floatx4*)(in + 4 * i);
        ushort4_t o;
        #pragma unroll
        for (int r = 0; r < 4; ++r)
            o[r] = f2bf(__builtin_amdgcn_exp2f(v[r] * LOG2E));
        *(ushort4_t*)(xp + 4 * i) = o;
    }
}

template<bool PRE>
__global__ __launch_bounds__(512, 2) void crf_main(
    const float* __restrict__ inputs, const float* __restrict__ trans,
    const int* __restrict__ tags, const int* __restrict__ mask,
    float* __restrict__ out, float* __restrict__ ws,
    const unsigned short* __restrict__ xp)
{
    __shared__ DenomShared sh;

    if (blockIdx.x >= ND) {
        // ---------------- numerator: one batch per block ----------------
        float* nred = sh.sbuf;              // [0,8)
        int*   nredi = (int*)(sh.sbuf + 8); // [8,16)
        const int bb = blockIdx.x - ND;
        const int t  = threadIdx.x;            // 0..511
        const int tg = tags[bb * T_ + t];
        const float fm = (float)mask[bb * T_ + t];
        float part = 0.f;
        if (t >= 1)      part += trans[tg * N_ + tags[bb * T_ + t - 1]] * fm;
        if (t <= T_ - 2) part += inputs[((size_t)bb * T_ + t) * N_ + tg] * fm;
        int ms = mask[bb * T_ + t];
        #pragma unroll
        for (int off = 1; off < 64; off <<= 1) {
            part += __shfl_xor(part, off, 64);
            ms   += __shfl_xor(ms, off, 64);
        }
        if ((t & 63) == 0) { nred[t >> 6] = part; nredi[t >> 6] = ms; }
        __syncthreads();
        if (t == 0) {
            float tot = 0.f; int mtot = 0;
            for (int i = 0; i < 8; ++i) { tot += nred[i]; mtot += nredi[i]; }
            tot += trans[tags[bb * T_] * N_ + START_];
            const int last = mtot - 1;
            const int lt = tags[bb * T_ + last];
            tot += trans[STOP_ * N_ + lt]
                 + inputs[((size_t)bb * T_ + (T_ - 1)) * N_ + lt]
                   * (float)mask[bb * T_ + T_ - 1];
            atomicAdd(out, tot);
        }
        return;
    }

    if (blockIdx.x < NF)
        denom_path<true,  PRE>(sh, inputs, trans, mask, xp, ws, blockIdx.x);
    else
        denom_path<false, PRE>(sh, inputs, trans, mask, xp, ws, blockIdx.x - NF);
}

// denom_b = LN2 * (CF_b + CB_b + log2(sum_j alphaF[b][j] * betaB[b][j]))
__global__ __launch_bounds__(256) void crf_combine(
    const float* __restrict__ ws, float* __restrict__ out)
{
    __shared__ float red[4];
    const int bb = blockIdx.x;
    const int t = threadIdx.x;
    float p = ws[(size_t)bb * N_ + t] * ws[WSB_OFF + (size_t)bb * N_ + t];
    #pragma unroll
    for (int off = 1; off < 64; off <<= 1) p += __shfl_xor(p, off, 64);
    if ((t & 63) == 0) red[t >> 6] = p;
    __syncthreads();
    if (t == 0) {
        const float tot = red[0] + red[1] + red[2] + red[3];
        const float denom = (ws[WCF_OFF + bb] + ws[WCB_OFF + bb]
                             + __builtin_amdgcn_logf(tot)) * LN2;
        atomicAdd(out, -denom);
    }
}

extern "C" void kernel_launch(void* const* d_in, const int* in_sizes, int n_in,
                              void* d_out, int out_size, void* d_ws, size_t ws_size,
                              hipStream_t stream) {
    const float* inputs = (const float*)d_in[0];
    const float* trans  = (const float*)d_in[1];
    const int*   tags   = (const int*)d_in[2];
    const int*   mask   = (const int*)d_in[3];
    float* out = (float*)d_out;
    float* ws  = (float*)d_ws;
    unsigned short* xp = (unsigned short*)((char*)d_ws + XP_BYTE_OFF);
    hipMemsetAsync(out, 0, sizeof(float), stream);
    if (ws_size >= WS_NEED) {
        crf_prepass<<<dim3(4096), dim3(512), 0, stream>>>(inputs, xp);
        crf_main<true><<<dim3(ND + B_), dim3(512), 0, stream>>>(
            inputs, trans, tags, mask, out, ws, xp);
    } else {
        crf_main<false><<<dim3(ND + B_), dim3(512), 0, stream>>>(
            inputs, trans, tags, mask, out, ws, xp);
    }
    crf_combine<<<dim3(B_), dim3(256), 0, stream>>>(ws, out);
}